// Round 2
// baseline (5216.545 us; speedup 1.0000x reference)
//
#include <hip/hip_runtime.h>
#include <math.h>

#define B_DIM 4
#define T_DIM 2048
#define D_DIM 1024
#define ETA 0.1f
#define N_ITERS 10

#define BM 128
#define BN 64
#define BK 16
#define APAD 4
#define BPAD 4

// ---------------------------------------------------------------------------
// Core fp32 tiled GEMM: C-tile(128x64) = A[m0:m0+128, kBegin:kEnd] * B
//   A is row-major [M x K], lda = K-stride.
//   B_NK = true : B stored [N x K] row-major (i.e. C = A * B^T)  -- "NT"
//   B_NK = false: B stored [K x N] row-major                     -- "NN"
// 256 threads, each computes 8x4 outputs. acc must be zeroed by caller.
// ---------------------------------------------------------------------------
template <bool B_NK>
__device__ __forceinline__ void gemm_core(const float* __restrict__ A,
                                          const float* __restrict__ Bm,
                                          int lda, int ldb, int m0, int n0,
                                          int kBegin, int kEnd,
                                          float acc[8][4]) {
  __shared__ float As[BK][BM + APAD];
  __shared__ float Bs[BK][BN + BPAD];
  const int tid = threadIdx.x;
  const int tx = tid & 15;   // -> n (4 wide)
  const int ty = tid >> 4;   // -> m (8 wide)

  for (int k0 = kBegin; k0 < kEnd; k0 += BK) {
    // ---- stage A tile (128x16): each thread 2x float4 along K, transposed
    {
      const int mbase = tid >> 2;
      const int kq = (tid & 3) << 2;
#pragma unroll
      for (int l = 0; l < 2; ++l) {
        const int m = mbase + l * 64;
        const float4 av =
            *(const float4*)(A + (size_t)(m0 + m) * lda + k0 + kq);
        As[kq + 0][m] = av.x;
        As[kq + 1][m] = av.y;
        As[kq + 2][m] = av.z;
        As[kq + 3][m] = av.w;
      }
    }
    // ---- stage B tile (16x64)
    if (B_NK) {
      const int n = tid >> 2;
      const int kq = (tid & 3) << 2;
      const float4 bv =
          *(const float4*)(Bm + (size_t)(n0 + n) * ldb + k0 + kq);
      Bs[kq + 0][n] = bv.x;
      Bs[kq + 1][n] = bv.y;
      Bs[kq + 2][n] = bv.z;
      Bs[kq + 3][n] = bv.w;
    } else {
      const int kk = tid >> 4;
      const int nq = (tid & 15) << 2;
      const float4 bv =
          *(const float4*)(Bm + (size_t)(k0 + kk) * ldb + n0 + nq);
      *(float4*)&Bs[kk][nq] = bv;  // row stride 68 floats -> 16B aligned
    }
    __syncthreads();

#pragma unroll
    for (int kk = 0; kk < BK; ++kk) {
      float af[8], bf[4];
#pragma unroll
      for (int i = 0; i < 8; ++i) af[i] = As[kk][ty * 8 + i];
#pragma unroll
      for (int j = 0; j < 4; ++j) bf[j] = Bs[kk][tx * 4 + j];
#pragma unroll
      for (int i = 0; i < 8; ++i)
#pragma unroll
        for (int j = 0; j < 4; ++j) acc[i][j] = fmaf(af[i], bf[j], acc[i][j]);
    }
    __syncthreads();
  }
}

__device__ __forceinline__ float soft_thresh(float v, float lam) {
  return copysignf(fmaxf(fabsf(v) - lam, 0.0f), v);
}

// ---------------------------------------------------------------------------
// G = 0.5*(Graw + Graw^T), zero diagonal
// ---------------------------------------------------------------------------
__global__ __launch_bounds__(256) void prep_G_kernel(
    const float* __restrict__ Graw, float* __restrict__ G) {
  const int idx = blockIdx.x * 256 + threadIdx.x;
  const int i = idx >> 10;
  const int j = idx & 1023;
  G[idx] = (i == j) ? 0.0f
                    : 0.5f * (Graw[idx] + Graw[(size_t)j * D_DIM + i]);
}

// ---------------------------------------------------------------------------
// Partial qkv: out columns [colOff + n0) of x @ Wqkv^T.
// dst = (n0>>10==0) ? dst0 : dst1, local column = n0 & 1023.
// ---------------------------------------------------------------------------
__global__ __launch_bounds__(256) void qkv_part_kernel(
    const float* __restrict__ x, const float* __restrict__ Wqkv,
    float* __restrict__ dst0, float* __restrict__ dst1, int colOff) {
  float acc[8][4] = {};
  const int m0 = blockIdx.y * BM;
  const int n0 = blockIdx.x * BN;
  gemm_core<true>(x, Wqkv, D_DIM, D_DIM, m0, colOff + n0, 0, D_DIM, acc);

  float* dst = ((n0 >> 10) == 0) ? dst0 : dst1;
  const int ncol = (n0 & 1023) + (threadIdx.x & 15) * 4;
  const int ty = threadIdx.x >> 4;
#pragma unroll
  for (int i = 0; i < 8; ++i) {
    const size_t m = m0 + ty * 8 + i;
    *(float4*)(dst + m * D_DIM + ncol) =
        make_float4(acc[i][0], acc[i][1], acc[i][2], acc[i][3]);
  }
}

// ---------------------------------------------------------------------------
// LCA iteration 0 (v=0, a=0):  v = ETA*u ; a = soft(v, lam)
// ---------------------------------------------------------------------------
__global__ __launch_bounds__(256) void lca_init_kernel(
    const float* __restrict__ u, float* __restrict__ vs,
    float* __restrict__ a, const float* __restrict__ log_lam) {
  const float lam = expf(log_lam[0]);
  const size_t i4 = ((size_t)blockIdx.x * 256 + threadIdx.x) * 4;
  const float4 uv = *(const float4*)(u + i4);
  float4 v;
  v.x = ETA * uv.x;
  v.y = ETA * uv.y;
  v.z = ETA * uv.z;
  v.w = ETA * uv.w;
  float4 av;
  av.x = soft_thresh(v.x, lam);
  av.y = soft_thresh(v.y, lam);
  av.z = soft_thresh(v.z, lam);
  av.w = soft_thresh(v.w, lam);
  *(float4*)(vs + i4) = v;
  *(float4*)(a + i4) = av;
}

// ---------------------------------------------------------------------------
// LCA iteration: t = a_in @ G ; v += ETA*(u - v - t) ; a_out = soft(v, lam)
// ---------------------------------------------------------------------------
__global__ __launch_bounds__(256) void lca_step_kernel(
    const float* __restrict__ a_in, const float* __restrict__ G,
    const float* __restrict__ u, float* __restrict__ vs,
    float* __restrict__ a_out, const float* __restrict__ log_lam) {
  float acc[8][4] = {};
  const int m0 = blockIdx.y * BM;
  const int n0 = blockIdx.x * BN;
  gemm_core<false>(a_in, G, D_DIM, D_DIM, m0, n0, 0, D_DIM, acc);

  const float lam = expf(log_lam[0]);
  const int tx = threadIdx.x & 15;
  const int ty = threadIdx.x >> 4;
#pragma unroll
  for (int i = 0; i < 8; ++i) {
    const size_t row = m0 + ty * 8 + i;
    const size_t base = row * D_DIM + n0 + tx * 4;
    float4 v4 = *(float4*)(vs + base);
    const float4 u4 = *(const float4*)(u + base);
    v4.x += ETA * (u4.x - v4.x - acc[i][0]);
    v4.y += ETA * (u4.y - v4.y - acc[i][1]);
    v4.z += ETA * (u4.z - v4.z - acc[i][2]);
    v4.w += ETA * (u4.w - v4.w - acc[i][3]);
    *(float4*)(vs + base) = v4;
    float4 a4;
    a4.x = soft_thresh(v4.x, lam);
    a4.y = soft_thresh(v4.y, lam);
    a4.z = soft_thresh(v4.z, lam);
    a4.w = soft_thresh(v4.w, lam);
    *(float4*)(a_out + base) = a4;
  }
}

// ---------------------------------------------------------------------------
// scores[b,i,j] = (aq[b,i,:] . ak[b,j,:]) / 32 ; skip strictly-upper blocks
// ---------------------------------------------------------------------------
__global__ __launch_bounds__(256) void scores_kernel(
    const float* __restrict__ aq, const float* __restrict__ ak,
    float* __restrict__ sc) {
  const int b = blockIdx.z;
  const int m0 = blockIdx.y * BM;
  const int n0 = blockIdx.x * BN;
  if (n0 > m0 + (BM - 1)) return;  // entire block is masked
  float acc[8][4] = {};
  gemm_core<true>(aq + (size_t)b * T_DIM * D_DIM,
                  ak + (size_t)b * T_DIM * D_DIM, D_DIM, D_DIM, m0, n0, 0,
                  D_DIM, acc);
  float* out = sc + (size_t)b * T_DIM * T_DIM;
  const float scale = 0.03125f;  // 1/sqrt(1024)
  const int tx = threadIdx.x & 15;
  const int ty = threadIdx.x >> 4;
#pragma unroll
  for (int i = 0; i < 8; ++i) {
    const size_t m = m0 + ty * 8 + i;
    *(float4*)(out + m * T_DIM + n0 + tx * 4) =
        make_float4(acc[i][0] * scale, acc[i][1] * scale, acc[i][2] * scale,
                    acc[i][3] * scale);
  }
}

// ---------------------------------------------------------------------------
// Causal softmax over row (b,i): uses scores[0..i], zero-fills j>i (in place)
// ---------------------------------------------------------------------------
__global__ __launch_bounds__(256) void softmax_kernel(float* __restrict__ sc) {
  const int b = blockIdx.x >> 11;
  const int i = blockIdx.x & (T_DIM - 1);
  float* row = sc + ((size_t)b * T_DIM + i) * T_DIM;
  const int len = i + 1;
  const int tid = threadIdx.x;
  __shared__ float red[256];

  float mx = -INFINITY;
  for (int j = tid; j < len; j += 256) mx = fmaxf(mx, row[j]);
  red[tid] = mx;
  __syncthreads();
  for (int s = 128; s > 0; s >>= 1) {
    if (tid < s) red[tid] = fmaxf(red[tid], red[tid + s]);
    __syncthreads();
  }
  mx = red[0];
  __syncthreads();

  float sum = 0.0f;
  for (int j = tid; j < len; j += 256) {
    const float e = expf(row[j] - mx);
    row[j] = e;
    sum += e;
  }
  red[tid] = sum;
  __syncthreads();
  for (int s = 128; s > 0; s >>= 1) {
    if (tid < s) red[tid] += red[tid + s];
    __syncthreads();
  }
  const float inv = 1.0f / red[0];

  for (int j = tid; j < len; j += 256) row[j] *= inv;
  for (int j = len + tid; j < T_DIM; j += 256) row[j] = 0.0f;
}

// ---------------------------------------------------------------------------
// o1[b,i,:] = attn[b,i,:] @ v[b]   (K capped at block row end: attn is 0 past i)
// ---------------------------------------------------------------------------
__global__ __launch_bounds__(256) void attnv_kernel(
    const float* __restrict__ attn, const float* __restrict__ vv,
    float* __restrict__ o1) {
  const int b = blockIdx.z;
  const int m0 = blockIdx.y * BM;
  const int n0 = blockIdx.x * BN;
  float acc[8][4] = {};
  gemm_core<false>(attn + (size_t)b * T_DIM * T_DIM,
                   vv + (size_t)b * T_DIM * D_DIM, T_DIM, D_DIM, m0, n0, 0,
                   m0 + BM, acc);
  float* out = o1 + (size_t)b * T_DIM * D_DIM;
  const int tx = threadIdx.x & 15;
  const int ty = threadIdx.x >> 4;
#pragma unroll
  for (int i = 0; i < 8; ++i) {
    const size_t m = m0 + ty * 8 + i;
    *(float4*)(out + m * D_DIM + n0 + tx * 4) =
        make_float4(acc[i][0], acc[i][1], acc[i][2], acc[i][3]);
  }
}

// ---------------------------------------------------------------------------
// out = o1 @ Wout^T
// ---------------------------------------------------------------------------
__global__ __launch_bounds__(256) void out_kernel(
    const float* __restrict__ o1, const float* __restrict__ Wout,
    float* __restrict__ out) {
  float acc[8][4] = {};
  const int m0 = blockIdx.y * BM;
  const int n0 = blockIdx.x * BN;
  gemm_core<true>(o1, Wout, D_DIM, D_DIM, m0, n0, 0, D_DIM, acc);
  const int tx = threadIdx.x & 15;
  const int ty = threadIdx.x >> 4;
#pragma unroll
  for (int i = 0; i < 8; ++i) {
    const size_t m = m0 + ty * 8 + i;
    *(float4*)(out + m * D_DIM + n0 + tx * 4) =
        make_float4(acc[i][0], acc[i][1], acc[i][2], acc[i][3]);
  }
}

// ---------------------------------------------------------------------------
// Workspace budget (floats), SZ = B*T*D = 8,388,608 (32 MiB):
//   buf0 = uq            -> later: scores low half
//   buf1 = uk            -> later: scores high half   (sc = 2*SZ exactly)
//   buf2 = v-state (q, then k) -> later: vv
//   buf3 = a ping A      -> later: o1
//   buf4 = a ping B (final aq)
//   + Gq, Gk (D*D each)
// Final ak lives in d_out (overwritten only by the last kernel).
// Total ws = 5*SZ + 2*D*D floats = 176,160,768 bytes (~168 MiB).
// ---------------------------------------------------------------------------
extern "C" void kernel_launch(void* const* d_in, const int* in_sizes, int n_in,
                              void* d_out, int out_size, void* d_ws,
                              size_t ws_size, hipStream_t stream) {
  (void)in_sizes;
  (void)n_in;
  (void)out_size;
  (void)ws_size;
  const float* x = (const float*)d_in[0];
  const float* Wqkv = (const float*)d_in[1];
  const float* Wout = (const float*)d_in[2];
  const float* Gq_raw = (const float*)d_in[3];
  const float* llq = (const float*)d_in[4];
  const float* Gk_raw = (const float*)d_in[5];
  const float* llk = (const float*)d_in[6];
  float* out = (float*)d_out;

  float* ws = (float*)d_ws;
  const size_t SZ = (size_t)B_DIM * T_DIM * D_DIM;  // 8,388,608
  float* uq = ws + 0 * SZ;
  float* uk = ws + 1 * SZ;
  float* vst = ws + 2 * SZ;
  float* aA = ws + 3 * SZ;
  float* aB = ws + 4 * SZ;
  float* Gq = ws + 5 * SZ;
  float* Gk = Gq + (size_t)D_DIM * D_DIM;
  // aliases (liveness-checked):
  float* sc = uq;    // scores: 2*SZ over dead uq+uk
  float* vv = vst;   // v computed after LCA, over dead v-state
  float* o1 = aA;    // attn@v output over dead ping buffer
  float* akf = out;  // final ak ping target = d_out (overwritten at end)

  const int MB = (B_DIM * T_DIM) / BM;  // 64
  const dim3 blk(256);

  prep_G_kernel<<<dim3((D_DIM * D_DIM) / 256), blk, 0, stream>>>(Gq_raw, Gq);
  prep_G_kernel<<<dim3((D_DIM * D_DIM) / 256), blk, 0, stream>>>(Gk_raw, Gk);

  // u_q, u_k = first 2048 columns of x @ Wqkv^T
  qkv_part_kernel<<<dim3((2 * D_DIM) / BN, MB), blk, 0, stream>>>(
      x, Wqkv, uq, uk, 0);

  const dim3 gl(D_DIM / BN, MB);
  const dim3 gi(SZ / 4 / 256);

  // ---- q LCA: ping aA <-> aB, 9 steps ends in aB
  lca_init_kernel<<<gi, blk, 0, stream>>>(uq, vst, aA, llq);
  {
    float* ping[2] = {aA, aB};
    int cur = 0;
    for (int it = 1; it < N_ITERS; ++it) {
      lca_step_kernel<<<gl, blk, 0, stream>>>(ping[cur], Gq, uq, vst,
                                              ping[1 - cur], llq);
      cur ^= 1;
    }
  }
  float* aq = aB;

  // ---- k LCA: ping aA <-> d_out, 9 steps ends in d_out
  lca_init_kernel<<<gi, blk, 0, stream>>>(uk, vst, aA, llk);
  {
    float* ping[2] = {aA, akf};
    int cur = 0;
    for (int it = 1; it < N_ITERS; ++it) {
      lca_step_kernel<<<gl, blk, 0, stream>>>(ping[cur], Gk, uk, vst,
                                              ping[1 - cur], llk);
      cur ^= 1;
    }
  }
  float* ak = akf;

  // ---- attention
  scores_kernel<<<dim3(T_DIM / BN, T_DIM / BM, B_DIM), blk, 0, stream>>>(
      aq, ak, sc);
  // vv = columns [2048,3072) of x @ Wqkv^T, into dead v-state buffer
  qkv_part_kernel<<<dim3(D_DIM / BN, MB), blk, 0, stream>>>(x, Wqkv, vv, vv,
                                                            2 * D_DIM);
  softmax_kernel<<<dim3(B_DIM * T_DIM), blk, 0, stream>>>(sc);
  attnv_kernel<<<dim3(D_DIM / BN, T_DIM / BM, B_DIM), blk, 0, stream>>>(
      sc, vv, o1);
  out_kernel<<<dim3(D_DIM / BN, MB), blk, 0, stream>>>(o1, Wout, out);
}

// Round 3
// 2491.237 us; speedup vs baseline: 2.0940x; 2.0940x over previous
//
#include <hip/hip_runtime.h>
#include <math.h>

#define B_DIM 4
#define T_DIM 2048
#define D_DIM 1024
#define ETA 0.1f
#define N_ITERS 10

typedef unsigned short u16;
typedef __attribute__((ext_vector_type(8))) short bf8_t;   // 8 bf16 (4 VGPRs)
typedef __attribute__((ext_vector_type(4))) float f4_t;    // 4 fp32 acc

__device__ __forceinline__ u16 f2bf(float f) {
  union { float f; unsigned u; } x;
  x.f = f;
  unsigned r = x.u + 0x7FFFu + ((x.u >> 16) & 1u);  // RNE
  return (u16)(r >> 16);
}

__device__ __forceinline__ float soft_thresh(float v, float lam) {
  return copysignf(fmaxf(fabsf(v) - lam, 0.0f), v);
}

// ---------------------------------------------------------------------------
// bf16 MFMA NT GEMM core: C(128x128 at m0,n0) = A[M x K] * B^T, where both
// A and B are row-major with K contiguous (B stored [N][K]).
// 256 threads = 4 waves (2x2), each wave 64x64 = 4x4 mfma 16x16x32 tiles.
// BK=64 staging, padded LDS rows (72 bf16 -> conflict-free b128 frag reads),
// register-prefetch software pipeline. kEnd must be a multiple of 64.
// ---------------------------------------------------------------------------
__device__ __forceinline__ void mfma_gemm_nt(const u16* __restrict__ A,
                                             const u16* __restrict__ Bm,
                                             int lda, int ldb,
                                             int m0, int n0, int kEnd,
                                             f4_t acc[4][4]) {
  __shared__ short As[128][72];
  __shared__ short Bs[128][72];
  const int tid = threadIdx.x;
  const int lane = tid & 63;
  const int wave = tid >> 6;
  const int m16 = lane & 15;
  const int q = lane >> 4;
  const int wrow = (wave >> 1) * 64;
  const int wcol = (wave & 1) * 64;
  const int sr = tid >> 3;   // staging row base (0..31)
  const int sc8 = tid & 7;   // k-octet (8 bf16 = 16B)

  float4 apf[4], bpf[4];
#pragma unroll
  for (int p = 0; p < 4; ++p) {
    apf[p] = *(const float4*)(A + (size_t)(m0 + sr + p * 32) * lda + sc8 * 8);
    bpf[p] = *(const float4*)(Bm + (size_t)(n0 + sr + p * 32) * ldb + sc8 * 8);
  }

  for (int k0 = 0; k0 < kEnd; k0 += 64) {
    __syncthreads();
#pragma unroll
    for (int p = 0; p < 4; ++p) {
      *(float4*)&As[sr + p * 32][sc8 * 8] = apf[p];
      *(float4*)&Bs[sr + p * 32][sc8 * 8] = bpf[p];
    }
    __syncthreads();
    if (k0 + 64 < kEnd) {
      const int kn = k0 + 64 + sc8 * 8;
#pragma unroll
      for (int p = 0; p < 4; ++p) {
        apf[p] = *(const float4*)(A + (size_t)(m0 + sr + p * 32) * lda + kn);
        bpf[p] = *(const float4*)(Bm + (size_t)(n0 + sr + p * 32) * ldb + kn);
      }
    }
#pragma unroll
    for (int s = 0; s < 2; ++s) {
      bf8_t af[4], bb[4];
#pragma unroll
      for (int i = 0; i < 4; ++i)
        af[i] = *(const bf8_t*)&As[wrow + i * 16 + m16][s * 32 + q * 8];
#pragma unroll
      for (int j = 0; j < 4; ++j)
        bb[j] = *(const bf8_t*)&Bs[wcol + j * 16 + m16][s * 32 + q * 8];
#pragma unroll
      for (int i = 0; i < 4; ++i)
#pragma unroll
        for (int j = 0; j < 4; ++j)
          acc[i][j] = __builtin_amdgcn_mfma_f32_16x16x32_bf16(
              af[i], bb[j], acc[i][j], 0, 0, 0);
    }
  }
}

// C/D layout (verified m89): col = lane&15, row = (lane>>4)*4 + reg.
#define EPI_PREAMBLE                                   \
  const int tid = threadIdx.x;                         \
  const int lane = tid & 63;                           \
  const int wave = tid >> 6;                           \
  const int m16 = lane & 15;                           \
  const int q = lane >> 4;                             \
  const int wrow = (wave >> 1) * 64;                   \
  const int wcol = (wave & 1) * 64;

// ---------------------------------------------------------------------------
// elementwise fp32 -> bf16 (n4 = count/4)
// ---------------------------------------------------------------------------
__global__ __launch_bounds__(256) void cvt_bf16_kernel(
    const float* __restrict__ src, u16* __restrict__ dst, int n4) {
  const int i = blockIdx.x * 256 + threadIdx.x;
  if (i >= n4) return;
  const float4 v = ((const float4*)src)[i];
  ushort4 o;
  o.x = f2bf(v.x); o.y = f2bf(v.y); o.z = f2bf(v.z); o.w = f2bf(v.w);
  ((ushort4*)dst)[i] = o;
}

// ---------------------------------------------------------------------------
// G = 0.5*(Graw+Graw^T), zero diag, to bf16 (symmetric -> NT-compatible)
// ---------------------------------------------------------------------------
__global__ __launch_bounds__(256) void prep_G_bf16_kernel(
    const float* __restrict__ Graw, u16* __restrict__ G) {
  const int idx = blockIdx.x * 256 + threadIdx.x;
  const int i = idx >> 10;
  const int j = idx & 1023;
  const float g =
      (i == j) ? 0.0f : 0.5f * (Graw[idx] + Graw[(size_t)j * D_DIM + i]);
  G[idx] = f2bf(g);
}

// ---------------------------------------------------------------------------
// qkv: [uq | uk | v] = x @ Wqkv^T. uq/uk stored fp32, v stored bf16.
// ---------------------------------------------------------------------------
__global__ __launch_bounds__(256) void qkv_mfma_kernel(
    const u16* __restrict__ xbf, const u16* __restrict__ Wbf,
    float* __restrict__ uq, float* __restrict__ uk, u16* __restrict__ vbf) {
  f4_t acc[4][4];
#pragma unroll
  for (int i = 0; i < 4; ++i)
#pragma unroll
    for (int j = 0; j < 4; ++j) acc[i][j] = (f4_t){0.f, 0.f, 0.f, 0.f};
  const int m0 = blockIdx.y * 128;
  const int n0 = blockIdx.x * 128;
  mfma_gemm_nt(xbf, Wbf, D_DIM, D_DIM, m0, n0, D_DIM, acc);
  EPI_PREAMBLE
  const int which = n0 >> 10;          // block never straddles a 1024 boundary
  const int nloc0 = n0 & 1023;
#pragma unroll
  for (int i = 0; i < 4; ++i)
#pragma unroll
    for (int j = 0; j < 4; ++j) {
      const int cc = nloc0 + wcol + j * 16 + m16;
#pragma unroll
      for (int r = 0; r < 4; ++r) {
        const size_t rr = m0 + wrow + i * 16 + q * 4 + r;
        const float val = acc[i][j][r];
        if (which == 0)       uq[rr * D_DIM + cc] = val;
        else if (which == 1)  uk[rr * D_DIM + cc] = val;
        else                  vbf[rr * D_DIM + cc] = f2bf(val);
      }
    }
}

// ---------------------------------------------------------------------------
// v [B][T][D] -> vT [B][D][T] (bf16), 64x64 tiles via LDS
// ---------------------------------------------------------------------------
__global__ __launch_bounds__(256) void transpose_bf16_kernel(
    const u16* __restrict__ src, u16* __restrict__ dst) {
  __shared__ short Ls[64][72];
  const int b = blockIdx.z;
  const int d0 = blockIdx.x * 64;
  const int t0 = blockIdx.y * 64;
  const int tid = threadIdx.x;
#pragma unroll
  for (int rep = 0; rep < 2; ++rep) {
    const int u = rep * 256 + tid;
    const int r = u >> 3;
    const int c8 = u & 7;
    const float4 v = *(const float4*)(src + (size_t)b * T_DIM * D_DIM +
                                      (size_t)(t0 + r) * D_DIM + d0 + c8 * 8);
    *(float4*)&Ls[r][c8 * 8] = v;
  }
  __syncthreads();
#pragma unroll
  for (int rep = 0; rep < 2; ++rep) {
    const int u = rep * 256 + tid;
    const int d = u >> 3;
    const int t8 = u & 7;
    union { u16 s[8]; float4 v; } tmp;
#pragma unroll
    for (int l = 0; l < 8; ++l) tmp.s[l] = (u16)Ls[t8 * 8 + l][d];
    *(float4*)(dst + (size_t)b * D_DIM * T_DIM + (size_t)(d0 + d) * T_DIM +
               t0 + t8 * 8) = tmp.v;
  }
}

// ---------------------------------------------------------------------------
// LCA iter 0: v = ETA*u ; a = soft(v, lam)  (v fp32, a bf16)
// ---------------------------------------------------------------------------
__global__ __launch_bounds__(256) void lca_init_kernel(
    const float* __restrict__ u, float* __restrict__ vs,
    u16* __restrict__ a, const float* __restrict__ log_lam) {
  const float lam = expf(log_lam[0]);
  const size_t i4 = ((size_t)blockIdx.x * 256 + threadIdx.x) * 4;
  const float4 uv = *(const float4*)(u + i4);
  float4 v;
  v.x = ETA * uv.x; v.y = ETA * uv.y; v.z = ETA * uv.z; v.w = ETA * uv.w;
  *(float4*)(vs + i4) = v;
  ushort4 av;
  av.x = f2bf(soft_thresh(v.x, lam));
  av.y = f2bf(soft_thresh(v.y, lam));
  av.z = f2bf(soft_thresh(v.z, lam));
  av.w = f2bf(soft_thresh(v.w, lam));
  *(ushort4*)(a + i4) = av;
}

// ---------------------------------------------------------------------------
// LCA step: t = a_in @ G (bf16 MFMA, G symmetric) ;
//           v += ETA*(u - v - t) ; a_out = soft(v, lam) -> bf16
// ---------------------------------------------------------------------------
__global__ __launch_bounds__(256) void lca_step_mfma_kernel(
    const u16* __restrict__ a_in, const u16* __restrict__ G,
    const float* __restrict__ u, float* __restrict__ vs,
    u16* __restrict__ a_out, const float* __restrict__ log_lam) {
  f4_t acc[4][4];
#pragma unroll
  for (int i = 0; i < 4; ++i)
#pragma unroll
    for (int j = 0; j < 4; ++j) acc[i][j] = (f4_t){0.f, 0.f, 0.f, 0.f};
  const int m0 = blockIdx.y * 128;
  const int n0 = blockIdx.x * 128;
  mfma_gemm_nt(a_in, G, D_DIM, D_DIM, m0, n0, D_DIM, acc);
  EPI_PREAMBLE
  const float lam = expf(log_lam[0]);
#pragma unroll
  for (int i = 0; i < 4; ++i)
#pragma unroll
    for (int j = 0; j < 4; ++j) {
      const int cc = n0 + wcol + j * 16 + m16;
#pragma unroll
      for (int r = 0; r < 4; ++r) {
        const size_t rr = m0 + wrow + i * 16 + q * 4 + r;
        const size_t base = rr * D_DIM + cc;
        float v = vs[base];
        v += ETA * (u[base] - v - acc[i][j][r]);
        vs[base] = v;
        a_out[base] = f2bf(soft_thresh(v, lam));
      }
    }
}

// ---------------------------------------------------------------------------
// scores = aq @ ak^T / 32 (fp32 out); skip blocks fully above the diagonal
// ---------------------------------------------------------------------------
__global__ __launch_bounds__(256) void scores_mfma_kernel(
    const u16* __restrict__ aq, const u16* __restrict__ ak,
    float* __restrict__ sc) {
  const int b = blockIdx.z;
  const int m0 = blockIdx.y * 128;
  const int n0 = blockIdx.x * 128;
  if (n0 > m0 + 127) return;  // uniform early exit, before any barrier
  f4_t acc[4][4];
#pragma unroll
  for (int i = 0; i < 4; ++i)
#pragma unroll
    for (int j = 0; j < 4; ++j) acc[i][j] = (f4_t){0.f, 0.f, 0.f, 0.f};
  mfma_gemm_nt(aq + (size_t)b * T_DIM * D_DIM,
               ak + (size_t)b * T_DIM * D_DIM, D_DIM, D_DIM, m0, n0, D_DIM,
               acc);
  EPI_PREAMBLE
  float* out = sc + (size_t)b * T_DIM * T_DIM;
  const float scale = 0.03125f;  // 1/sqrt(1024)
#pragma unroll
  for (int i = 0; i < 4; ++i)
#pragma unroll
    for (int j = 0; j < 4; ++j) {
      const int cc = n0 + wcol + j * 16 + m16;
#pragma unroll
      for (int r = 0; r < 4; ++r) {
        const size_t rr = m0 + wrow + i * 16 + q * 4 + r;
        out[rr * T_DIM + cc] = acc[i][j][r] * scale;
      }
    }
}

// ---------------------------------------------------------------------------
// Causal softmax row (b,i): reads sc fp32 j<=i, writes attn bf16 (0 for j>i)
// ---------------------------------------------------------------------------
__global__ __launch_bounds__(256) void softmax_attn_kernel(
    const float* __restrict__ sc, u16* __restrict__ attn) {
  const int b = blockIdx.x >> 11;
  const int i = blockIdx.x & (T_DIM - 1);
  const float* row = sc + ((size_t)b * T_DIM + i) * T_DIM;
  u16* arow = attn + ((size_t)b * T_DIM + i) * T_DIM;
  const int len = i + 1;
  const int tid = threadIdx.x;
  __shared__ float red[256];

  float mx = -INFINITY;
  for (int j = tid; j < len; j += 256) mx = fmaxf(mx, row[j]);
  red[tid] = mx;
  __syncthreads();
  for (int s = 128; s > 0; s >>= 1) {
    if (tid < s) red[tid] = fmaxf(red[tid], red[tid + s]);
    __syncthreads();
  }
  mx = red[0];
  __syncthreads();

  float sum = 0.0f;
  for (int j = tid; j < len; j += 256) sum += __expf(row[j] - mx);
  red[tid] = sum;
  __syncthreads();
  for (int s = 128; s > 0; s >>= 1) {
    if (tid < s) red[tid] += red[tid + s];
    __syncthreads();
  }
  const float inv = 1.0f / red[0];

  for (int j = tid; j < len; j += 256)
    arow[j] = f2bf(__expf(row[j] - mx) * inv);
  for (int j = len + tid; j < T_DIM; j += 256) arow[j] = 0;
}

// ---------------------------------------------------------------------------
// o1 = attn @ v  via NT with vT [B][D][T]; K capped at m0+128 (attn 0 beyond)
// ---------------------------------------------------------------------------
__global__ __launch_bounds__(256) void attnv_mfma_kernel(
    const u16* __restrict__ attn, const u16* __restrict__ vT,
    u16* __restrict__ o1) {
  const int b = blockIdx.z;
  const int m0 = blockIdx.y * 128;
  const int n0 = blockIdx.x * 128;
  f4_t acc[4][4];
#pragma unroll
  for (int i = 0; i < 4; ++i)
#pragma unroll
    for (int j = 0; j < 4; ++j) acc[i][j] = (f4_t){0.f, 0.f, 0.f, 0.f};
  mfma_gemm_nt(attn + (size_t)b * T_DIM * T_DIM,
               vT + (size_t)b * D_DIM * T_DIM, T_DIM, T_DIM, m0, n0,
               m0 + 128, acc);
  EPI_PREAMBLE
  u16* out = o1 + (size_t)b * T_DIM * D_DIM;
#pragma unroll
  for (int i = 0; i < 4; ++i)
#pragma unroll
    for (int j = 0; j < 4; ++j) {
      const int cc = n0 + wcol + j * 16 + m16;
#pragma unroll
      for (int r = 0; r < 4; ++r) {
        const size_t rr = m0 + wrow + i * 16 + q * 4 + r;
        out[rr * D_DIM + cc] = f2bf(acc[i][j][r]);
      }
    }
}

// ---------------------------------------------------------------------------
// out = o1 @ Wout^T (fp32 out)
// ---------------------------------------------------------------------------
__global__ __launch_bounds__(256) void out_mfma_kernel(
    const u16* __restrict__ o1, const u16* __restrict__ Wbf,
    float* __restrict__ out) {
  f4_t acc[4][4];
#pragma unroll
  for (int i = 0; i < 4; ++i)
#pragma unroll
    for (int j = 0; j < 4; ++j) acc[i][j] = (f4_t){0.f, 0.f, 0.f, 0.f};
  const int m0 = blockIdx.y * 128;
  const int n0 = blockIdx.x * 128;
  mfma_gemm_nt(o1, Wbf, D_DIM, D_DIM, m0, n0, D_DIM, acc);
  EPI_PREAMBLE
#pragma unroll
  for (int i = 0; i < 4; ++i)
#pragma unroll
    for (int j = 0; j < 4; ++j) {
      const int cc = n0 + wcol + j * 16 + m16;
#pragma unroll
      for (int r = 0; r < 4; ++r) {
        const size_t rr = m0 + wrow + i * 16 + q * 4 + r;
        out[rr * D_DIM + cc] = acc[i][j][r];
      }
    }
}

// ---------------------------------------------------------------------------
// Workspace (SZ = B*T*D = 8,388,608):
//   fp32:  uq (SZ), vstate (SZ)                            [64 MiB]
//   bf16:  xbf/vT (SZ), vbf (SZ), bq0 (SZ), bq1 (SZ), bkf (SZ),
//          Wqkv (3M), Wout (1M), Gq (1M), Gk (1M)          [~92 MiB]
// Total ~156 MiB. u_k lives in d_out (overwritten by the final GEMM).
// Aliases: sc(fp32, 2*SZ) over [uq|vstate]; attn(bf16, 2*SZ) over [vbf|bq0];
//          vT over xbf; o1 over bq1. Liveness verified launch-by-launch.
// ---------------------------------------------------------------------------
extern "C" void kernel_launch(void* const* d_in, const int* in_sizes, int n_in,
                              void* d_out, int out_size, void* d_ws,
                              size_t ws_size, hipStream_t stream) {
  (void)in_sizes; (void)n_in; (void)out_size; (void)ws_size;
  const float* x = (const float*)d_in[0];
  const float* Wqkv = (const float*)d_in[1];
  const float* Wout = (const float*)d_in[2];
  const float* Gq_raw = (const float*)d_in[3];
  const float* llq = (const float*)d_in[4];
  const float* Gk_raw = (const float*)d_in[5];
  const float* llk = (const float*)d_in[6];
  float* out = (float*)d_out;

  const size_t SZ = (size_t)B_DIM * T_DIM * D_DIM;  // 8,388,608
  float* ws = (float*)d_ws;
  float* uq = ws;                 // SZ fp32
  float* vst = ws + SZ;           // SZ fp32
  u16* bstart = (u16*)(ws + 2 * SZ);
  u16* xbf = bstart;              // SZ bf16 (later vT)
  u16* vbf = bstart + SZ;         // SZ
  u16* bq0 = bstart + 2 * SZ;     // SZ
  u16* bq1 = bstart + 3 * SZ;     // SZ  (final aq; later o1)
  u16* bkf = bstart + 4 * SZ;     // SZ  (final ak)
  u16* wqkvb = bstart + 5 * SZ;                  // 3M
  u16* woutb = wqkvb + 3 * 1024 * 1024;          // 1M
  u16* gqb = woutb + 1024 * 1024;                // 1M
  u16* gkb = gqb + 1024 * 1024;                  // 1M
  // aliases
  float* uk = out;                // d_out hosts u_k until the final GEMM
  float* sc = uq;                 // 2*SZ fp32 over uq+vstate
  u16* vT = xbf;                  // after qkv, xbf is dead
  u16* attn = vbf;                // 2*SZ bf16 over vbf+bq0 (both dead)
  u16* o1 = bq1;                  // after scores, aq is dead

  const dim3 blk(256);

  cvt_bf16_kernel<<<dim3((int)(SZ / 4 / 256)), blk, 0, stream>>>(x, xbf,
                                                                 (int)(SZ / 4));
  cvt_bf16_kernel<<<dim3(3 * 1024), blk, 0, stream>>>(Wqkv, wqkvb,
                                                      3 * 1024 * 1024 / 4);
  cvt_bf16_kernel<<<dim3(1024), blk, 0, stream>>>(Wout, woutb,
                                                  1024 * 1024 / 4);
  prep_G_bf16_kernel<<<dim3(4096), blk, 0, stream>>>(Gq_raw, gqb);
  prep_G_bf16_kernel<<<dim3(4096), blk, 0, stream>>>(Gk_raw, gkb);

  // qkv: grid (3072/128, 8192/128)
  qkv_mfma_kernel<<<dim3(24, 64), blk, 0, stream>>>(xbf, wqkvb, uq, uk, vbf);
  // vT (xbf dead now)
  transpose_bf16_kernel<<<dim3(16, 32, 4), blk, 0, stream>>>(vbf, vT);

  const dim3 gl(8, 64);  // 1024/128, 8192/128
  const dim3 gi((int)(SZ / 4 / 256));

  // q-chain: init->bq0, 9 steps ping bq0<->bq1, ends in bq1
  lca_init_kernel<<<gi, blk, 0, stream>>>(uq, vst, bq0, llq);
  {
    u16* ping[2] = {bq0, bq1};
    int cur = 0;
    for (int it = 1; it < N_ITERS; ++it) {
      lca_step_mfma_kernel<<<gl, blk, 0, stream>>>(ping[cur], gqb, uq, vst,
                                                   ping[1 - cur], llq);
      cur ^= 1;
    }
  }
  // k-chain: init->bq0, 9 steps ping bq0<->bkf, ends in bkf
  lca_init_kernel<<<gi, blk, 0, stream>>>(uk, vst, bq0, llk);
  {
    u16* ping[2] = {bq0, bkf};
    int cur = 0;
    for (int it = 1; it < N_ITERS; ++it) {
      lca_step_mfma_kernel<<<gl, blk, 0, stream>>>(ping[cur], gkb, uk, vst,
                                                   ping[1 - cur], llk);
      cur ^= 1;
    }
  }

  scores_mfma_kernel<<<dim3(16, 16, 4), blk, 0, stream>>>(bq1, bkf, sc);
  softmax_attn_kernel<<<dim3(B_DIM * T_DIM), blk, 0, stream>>>(sc, attn);
  attnv_mfma_kernel<<<dim3(8, 16, 4), blk, 0, stream>>>(attn, vT, o1);
  out_mfma_kernel<<<dim3(8, 64), blk, 0, stream>>>(o1, woutb, out);
}

// Round 4
// 2038.077 us; speedup vs baseline: 2.5595x; 1.2223x over previous
//
#include <hip/hip_runtime.h>
#include <math.h>

#define B_DIM 4
#define T_DIM 2048
#define D_DIM 1024
#define ETA 0.1f
#define N_ITERS 10

typedef unsigned short u16;
typedef __attribute__((ext_vector_type(8))) short bf8_t;   // 8 bf16 (4 VGPRs)
typedef __attribute__((ext_vector_type(4))) float f4_t;    // 4 fp32 acc

__device__ __forceinline__ u16 f2bf(float f) {
  union { float f; unsigned u; } x;
  x.f = f;
  unsigned r = x.u + 0x7FFFu + ((x.u >> 16) & 1u);  // RNE
  return (u16)(r >> 16);
}

__device__ __forceinline__ float soft_thresh(float v, float lam) {
  return copysignf(fmaxf(fabsf(v) - lam, 0.0f), v);
}

// ---------------------------------------------------------------------------
// bf16 MFMA NT GEMM core: C(128x128 at m0,n0) = A[M x K] * B^T (B is [N][K]).
// 256 threads = 4 waves (2x2), each wave 64x64 = 4x4 mfma 16x16x32 tiles.
// ---------------------------------------------------------------------------
__device__ __forceinline__ void mfma_gemm_nt(const u16* __restrict__ A,
                                             const u16* __restrict__ Bm,
                                             int lda, int ldb,
                                             int m0, int n0, int kEnd,
                                             f4_t acc[4][4]) {
  __shared__ short As[128][72];
  __shared__ short Bs[128][72];
  const int tid = threadIdx.x;
  const int lane = tid & 63;
  const int wave = tid >> 6;
  const int m16 = lane & 15;
  const int q = lane >> 4;
  const int wrow = (wave >> 1) * 64;
  const int wcol = (wave & 1) * 64;
  const int sr = tid >> 3;   // staging row base (0..31)
  const int sc8 = tid & 7;   // k-octet (8 bf16 = 16B)

  float4 apf[4], bpf[4];
#pragma unroll
  for (int p = 0; p < 4; ++p) {
    apf[p] = *(const float4*)(A + (size_t)(m0 + sr + p * 32) * lda + sc8 * 8);
    bpf[p] = *(const float4*)(Bm + (size_t)(n0 + sr + p * 32) * ldb + sc8 * 8);
  }

  for (int k0 = 0; k0 < kEnd; k0 += 64) {
    __syncthreads();
#pragma unroll
    for (int p = 0; p < 4; ++p) {
      *(float4*)&As[sr + p * 32][sc8 * 8] = apf[p];
      *(float4*)&Bs[sr + p * 32][sc8 * 8] = bpf[p];
    }
    __syncthreads();
    if (k0 + 64 < kEnd) {
      const int kn = k0 + 64 + sc8 * 8;
#pragma unroll
      for (int p = 0; p < 4; ++p) {
        apf[p] = *(const float4*)(A + (size_t)(m0 + sr + p * 32) * lda + kn);
        bpf[p] = *(const float4*)(Bm + (size_t)(n0 + sr + p * 32) * ldb + kn);
      }
    }
#pragma unroll
    for (int s = 0; s < 2; ++s) {
      bf8_t af[4], bb[4];
#pragma unroll
      for (int i = 0; i < 4; ++i)
        af[i] = *(const bf8_t*)&As[wrow + i * 16 + m16][s * 32 + q * 8];
#pragma unroll
      for (int j = 0; j < 4; ++j)
        bb[j] = *(const bf8_t*)&Bs[wcol + j * 16 + m16][s * 32 + q * 8];
#pragma unroll
      for (int i = 0; i < 4; ++i)
#pragma unroll
        for (int j = 0; j < 4; ++j)
          acc[i][j] = __builtin_amdgcn_mfma_f32_16x16x32_bf16(
              af[i], bb[j], acc[i][j], 0, 0, 0);
    }
  }
}

// C/D layout (verified m89): col = lane&15, row = (lane>>4)*4 + reg.
#define EPI_PREAMBLE                                   \
  const int tid = threadIdx.x;                         \
  const int lane = tid & 63;                           \
  const int wave = tid >> 6;                           \
  const int m16 = lane & 15;                           \
  const int q = lane >> 4;                             \
  const int wrow = (wave >> 1) * 64;                   \
  const int wcol = (wave & 1) * 64;

// ---------------------------------------------------------------------------
__global__ __launch_bounds__(256) void cvt_bf16_kernel(
    const float* __restrict__ src, u16* __restrict__ dst, int n4) {
  const int i = blockIdx.x * 256 + threadIdx.x;
  if (i >= n4) return;
  const float4 v = ((const float4*)src)[i];
  ushort4 o;
  o.x = f2bf(v.x); o.y = f2bf(v.y); o.z = f2bf(v.z); o.w = f2bf(v.w);
  ((ushort4*)dst)[i] = o;
}

// ---------------------------------------------------------------------------
__global__ __launch_bounds__(256) void prep_G_bf16_kernel(
    const float* __restrict__ Graw, u16* __restrict__ G) {
  const int idx = blockIdx.x * 256 + threadIdx.x;
  const int i = idx >> 10;
  const int j = idx & 1023;
  const float g =
      (i == j) ? 0.0f : 0.5f * (Graw[idx] + Graw[(size_t)j * D_DIM + i]);
  G[idx] = f2bf(g);
}

// ---------------------------------------------------------------------------
// qkv = x @ Wqkv^T. 1-D grid of 1536 blocks, supertile-swizzled:
// groups of 192 blocks cover 8 m-blocks x 24 n-blocks, so each XCD's L2
// holds a small W slice + x panel (kills the 751 MB over-fetch of R3).
// ---------------------------------------------------------------------------
__global__ __launch_bounds__(256) void qkv_mfma_kernel(
    const u16* __restrict__ xbf, const u16* __restrict__ Wbf,
    float* __restrict__ uq, float* __restrict__ uk, u16* __restrict__ vbf) {
  const int bid = blockIdx.x;
  const int g = bid / 192;
  const int r = bid % 192;
  const int m0 = (g * 8 + (r & 7)) * 128;
  const int n0 = (r >> 3) * 128;
  f4_t acc[4][4];
#pragma unroll
  for (int i = 0; i < 4; ++i)
#pragma unroll
    for (int j = 0; j < 4; ++j) acc[i][j] = (f4_t){0.f, 0.f, 0.f, 0.f};
  mfma_gemm_nt(xbf, Wbf, D_DIM, D_DIM, m0, n0, D_DIM, acc);
  EPI_PREAMBLE
  const int which = n0 >> 10;
  const int nloc0 = n0 & 1023;
#pragma unroll
  for (int i = 0; i < 4; ++i)
#pragma unroll
    for (int j = 0; j < 4; ++j) {
      const int cc = nloc0 + wcol + j * 16 + m16;
#pragma unroll
      for (int r2 = 0; r2 < 4; ++r2) {
        const size_t rr = m0 + wrow + i * 16 + q * 4 + r2;
        const float val = acc[i][j][r2];
        if (which == 0)       uq[rr * D_DIM + cc] = val;
        else if (which == 1)  uk[rr * D_DIM + cc] = val;
        else                  vbf[rr * D_DIM + cc] = f2bf(val);
      }
    }
}

// ---------------------------------------------------------------------------
__global__ __launch_bounds__(256) void transpose_bf16_kernel(
    const u16* __restrict__ src, u16* __restrict__ dst) {
  __shared__ short Ls[64][72];
  const int b = blockIdx.z;
  const int d0 = blockIdx.x * 64;
  const int t0 = blockIdx.y * 64;
  const int tid = threadIdx.x;
#pragma unroll
  for (int rep = 0; rep < 2; ++rep) {
    const int u = rep * 256 + tid;
    const int r = u >> 3;
    const int c8 = u & 7;
    const float4 v = *(const float4*)(src + (size_t)b * T_DIM * D_DIM +
                                      (size_t)(t0 + r) * D_DIM + d0 + c8 * 8);
    *(float4*)&Ls[r][c8 * 8] = v;
  }
  __syncthreads();
#pragma unroll
  for (int rep = 0; rep < 2; ++rep) {
    const int u = rep * 256 + tid;
    const int d = u >> 3;
    const int t8 = u & 7;
    union { u16 s[8]; float4 v; } tmp;
#pragma unroll
    for (int l = 0; l < 8; ++l) tmp.s[l] = (u16)Ls[t8 * 8 + l][d];
    *(float4*)(dst + (size_t)b * D_DIM * T_DIM + (size_t)(d0 + d) * T_DIM +
               t0 + t8 * 8) = tmp.v;
  }
}

// ---------------------------------------------------------------------------
// Fused LCA chain: all 10 iterations in one kernel.
// Block owns 32 rows. u,v resident in VGPRs; a ping-pongs in LDS (2x66 KB);
// G (symmetric, bf16) streamed from L2 each iteration via NT fragment loads.
// Grid 512: blockIdx%8 in 0..3 -> q-chain (XCD 0-3), 4..7 -> k-chain, so each
// XCD's 4 MB L2 only holds one 2 MB G.
// Per wave: n-slice 256 cols, processed in two halves of 128 (acc pressure).
// ---------------------------------------------------------------------------
__global__ __launch_bounds__(256, 1) void lca_fused_kernel(
    const float* __restrict__ uqg, const float* __restrict__ ukg,
    const u16* __restrict__ Gq, const u16* __restrict__ Gk,
    const float* __restrict__ llq, const float* __restrict__ llk,
    u16* __restrict__ aq_out, u16* __restrict__ ak_out) {
  __shared__ u16 a_lds[2][32][1032];  // +8 pad: conflict-free b128 reads
  const int b = blockIdx.x;
  const int chain = (b >> 2) & 1;                 // b%8: 0-3 q, 4-7 k
  const int mb = ((b >> 3) << 2) | (b & 3);       // 0..255
  const int m0 = mb * 32;
  const float* __restrict__ u = chain ? ukg : uqg;
  const u16* __restrict__ G = chain ? Gk : Gq;
  u16* __restrict__ aout = chain ? ak_out : aq_out;
  const float lam = expf(chain ? llk[0] : llq[0]);

  const int tid = threadIdx.x;
  const int lane = tid & 63;
  const int wave = tid >> 6;
  const int m16 = lane & 15;
  const int q = lane >> 4;
  const int n0w = wave * 256;

  float vreg[2][16][4];
  float ureg[2][16][4];

  // load u into registers + iteration 0: v = ETA*u, a0 = soft(v)
#pragma unroll
  for (int rt = 0; rt < 2; ++rt)
#pragma unroll
    for (int ct = 0; ct < 16; ++ct) {
      const int row = rt * 16 + q * 4;
      const int col = n0w + ct * 16 + m16;
#pragma unroll
      for (int r = 0; r < 4; ++r) {
        const float uv = u[(size_t)(m0 + row + r) * D_DIM + col];
        ureg[rt][ct][r] = uv;
        const float v = ETA * uv;
        vreg[rt][ct][r] = v;
        a_lds[0][row + r][col] = f2bf(soft_thresh(v, lam));
      }
    }

  int cur = 0;
  for (int it = 1; it < N_ITERS; ++it) {
    __syncthreads();  // a_lds[cur] complete (init or previous epilogue)
    const bool last = (it == N_ITERS - 1);
#pragma unroll
    for (int h = 0; h < 2; ++h) {
      f4_t acc[2][8];
#pragma unroll
      for (int rt = 0; rt < 2; ++rt)
#pragma unroll
        for (int ct = 0; ct < 8; ++ct) acc[rt][ct] = (f4_t){0.f, 0.f, 0.f, 0.f};

      const u16* gbase = G + (size_t)(n0w + h * 128 + m16) * D_DIM + q * 8;
#pragma unroll 2
      for (int k0 = 0; k0 < D_DIM; k0 += 32) {
        const bf8_t af0 = *(const bf8_t*)&a_lds[cur][m16][k0 + q * 8];
        const bf8_t af1 = *(const bf8_t*)&a_lds[cur][16 + m16][k0 + q * 8];
        bf8_t bb[8];
#pragma unroll
        for (int ct = 0; ct < 8; ++ct)
          bb[ct] = *(const bf8_t*)(gbase + (size_t)ct * 16 * D_DIM + k0);
#pragma unroll
        for (int ct = 0; ct < 8; ++ct) {
          acc[0][ct] = __builtin_amdgcn_mfma_f32_16x16x32_bf16(
              af0, bb[ct], acc[0][ct], 0, 0, 0);
          acc[1][ct] = __builtin_amdgcn_mfma_f32_16x16x32_bf16(
              af1, bb[ct], acc[1][ct], 0, 0, 0);
        }
      }
      // epilogue half: update v, write a_next into the other LDS buffer
#pragma unroll
      for (int rt = 0; rt < 2; ++rt)
#pragma unroll
        for (int c8 = 0; c8 < 8; ++c8) {
          const int ct = h * 8 + c8;
          const int row = rt * 16 + q * 4;
          const int col = n0w + ct * 16 + m16;
#pragma unroll
          for (int r = 0; r < 4; ++r) {
            float v = vreg[rt][ct][r];
            v += ETA * (ureg[rt][ct][r] - v - acc[rt][c8][r]);
            vreg[rt][ct][r] = v;
            const u16 av = f2bf(soft_thresh(v, lam));
            a_lds[cur ^ 1][row + r][col] = av;
            if (last) aout[(size_t)(m0 + row + r) * D_DIM + col] = av;
          }
        }
    }
    cur ^= 1;
  }
}

// ---------------------------------------------------------------------------
__global__ __launch_bounds__(256) void scores_mfma_kernel(
    const u16* __restrict__ aq, const u16* __restrict__ ak,
    float* __restrict__ sc) {
  const int b = blockIdx.z;
  const int m0 = blockIdx.y * 128;
  const int n0 = blockIdx.x * 128;
  if (n0 > m0 + 127) return;  // uniform early exit, before any barrier
  f4_t acc[4][4];
#pragma unroll
  for (int i = 0; i < 4; ++i)
#pragma unroll
    for (int j = 0; j < 4; ++j) acc[i][j] = (f4_t){0.f, 0.f, 0.f, 0.f};
  mfma_gemm_nt(aq + (size_t)b * T_DIM * D_DIM,
               ak + (size_t)b * T_DIM * D_DIM, D_DIM, D_DIM, m0, n0, D_DIM,
               acc);
  EPI_PREAMBLE
  float* out = sc + (size_t)b * T_DIM * T_DIM;
  const float scale = 0.03125f;  // 1/sqrt(1024)
#pragma unroll
  for (int i = 0; i < 4; ++i)
#pragma unroll
    for (int j = 0; j < 4; ++j) {
      const int cc = n0 + wcol + j * 16 + m16;
#pragma unroll
      for (int r = 0; r < 4; ++r) {
        const size_t rr = m0 + wrow + i * 16 + q * 4 + r;
        out[rr * T_DIM + cc] = acc[i][j][r] * scale;
      }
    }
}

// ---------------------------------------------------------------------------
__global__ __launch_bounds__(256) void softmax_attn_kernel(
    const float* __restrict__ sc, u16* __restrict__ attn) {
  const int b = blockIdx.x >> 11;
  const int i = blockIdx.x & (T_DIM - 1);
  const float* row = sc + ((size_t)b * T_DIM + i) * T_DIM;
  u16* arow = attn + ((size_t)b * T_DIM + i) * T_DIM;
  const int len = i + 1;
  const int tid = threadIdx.x;
  __shared__ float red[256];

  float mx = -INFINITY;
  for (int j = tid; j < len; j += 256) mx = fmaxf(mx, row[j]);
  red[tid] = mx;
  __syncthreads();
  for (int s = 128; s > 0; s >>= 1) {
    if (tid < s) red[tid] = fmaxf(red[tid], red[tid + s]);
    __syncthreads();
  }
  mx = red[0];
  __syncthreads();

  float sum = 0.0f;
  for (int j = tid; j < len; j += 256) sum += __expf(row[j] - mx);
  red[tid] = sum;
  __syncthreads();
  for (int s = 128; s > 0; s >>= 1) {
    if (tid < s) red[tid] += red[tid + s];
    __syncthreads();
  }
  const float inv = 1.0f / red[0];

  for (int j = tid; j < len; j += 256)
    arow[j] = f2bf(__expf(row[j] - mx) * inv);
  for (int j = len + tid; j < T_DIM; j += 256) arow[j] = 0;
}

// ---------------------------------------------------------------------------
__global__ __launch_bounds__(256) void attnv_mfma_kernel(
    const u16* __restrict__ attn, const u16* __restrict__ vT,
    u16* __restrict__ o1) {
  const int b = blockIdx.z;
  const int m0 = blockIdx.y * 128;
  const int n0 = blockIdx.x * 128;
  f4_t acc[4][4];
#pragma unroll
  for (int i = 0; i < 4; ++i)
#pragma unroll
    for (int j = 0; j < 4; ++j) acc[i][j] = (f4_t){0.f, 0.f, 0.f, 0.f};
  mfma_gemm_nt(attn + (size_t)b * T_DIM * T_DIM,
               vT + (size_t)b * D_DIM * T_DIM, T_DIM, T_DIM, m0, n0,
               m0 + 128, acc);
  EPI_PREAMBLE
  u16* out = o1 + (size_t)b * T_DIM * D_DIM;
#pragma unroll
  for (int i = 0; i < 4; ++i)
#pragma unroll
    for (int j = 0; j < 4; ++j) {
      const int cc = n0 + wcol + j * 16 + m16;
#pragma unroll
      for (int r = 0; r < 4; ++r) {
        const size_t rr = m0 + wrow + i * 16 + q * 4 + r;
        out[rr * D_DIM + cc] = f2bf(acc[i][j][r]);
      }
    }
}

// ---------------------------------------------------------------------------
__global__ __launch_bounds__(256) void out_mfma_kernel(
    const u16* __restrict__ o1, const u16* __restrict__ Wbf,
    float* __restrict__ out) {
  f4_t acc[4][4];
#pragma unroll
  for (int i = 0; i < 4; ++i)
#pragma unroll
    for (int j = 0; j < 4; ++j) acc[i][j] = (f4_t){0.f, 0.f, 0.f, 0.f};
  const int m0 = blockIdx.y * 128;
  const int n0 = blockIdx.x * 128;
  mfma_gemm_nt(o1, Wbf, D_DIM, D_DIM, m0, n0, D_DIM, acc);
  EPI_PREAMBLE
#pragma unroll
  for (int i = 0; i < 4; ++i)
#pragma unroll
    for (int j = 0; j < 4; ++j) {
      const int cc = n0 + wcol + j * 16 + m16;
#pragma unroll
      for (int r = 0; r < 4; ++r) {
        const size_t rr = m0 + wrow + i * 16 + q * 4 + r;
        out[rr * D_DIM + cc] = acc[i][j][r];
      }
    }
}

// ---------------------------------------------------------------------------
// Workspace layout identical to R3 (~156 MiB, passed). bq0 is now unused by
// LCA (fused kernel writes final a directly) but still backs the attn alias.
// ---------------------------------------------------------------------------
extern "C" void kernel_launch(void* const* d_in, const int* in_sizes, int n_in,
                              void* d_out, int out_size, void* d_ws,
                              size_t ws_size, hipStream_t stream) {
  (void)in_sizes; (void)n_in; (void)out_size; (void)ws_size;
  const float* x = (const float*)d_in[0];
  const float* Wqkv = (const float*)d_in[1];
  const float* Wout = (const float*)d_in[2];
  const float* Gq_raw = (const float*)d_in[3];
  const float* llq = (const float*)d_in[4];
  const float* Gk_raw = (const float*)d_in[5];
  const float* llk = (const float*)d_in[6];
  float* out = (float*)d_out;

  const size_t SZ = (size_t)B_DIM * T_DIM * D_DIM;  // 8,388,608
  float* ws = (float*)d_ws;
  float* uq = ws;                 // SZ fp32
  float* vst = ws + SZ;           // SZ fp32 (only used as scores space now)
  u16* bstart = (u16*)(ws + 2 * SZ);
  u16* xbf = bstart;              // SZ bf16 (later vT)
  u16* vbf = bstart + SZ;         // SZ
  u16* bq0 = bstart + 2 * SZ;     // SZ (attn alias space)
  u16* bq1 = bstart + 3 * SZ;     // SZ  (final aq; later o1)
  u16* bkf = bstart + 4 * SZ;     // SZ  (final ak)
  u16* wqkvb = bstart + 5 * SZ;                  // 3M
  u16* woutb = wqkvb + 3 * 1024 * 1024;          // 1M
  u16* gqb = woutb + 1024 * 1024;                // 1M
  u16* gkb = gqb + 1024 * 1024;                  // 1M
  (void)bq0;
  // aliases
  float* uk = out;                // d_out hosts u_k until the final GEMM
  float* sc = uq;                 // 2*SZ fp32 over uq+vst
  u16* vT = xbf;                  // after qkv, xbf is dead
  u16* attn = vbf;                // 2*SZ bf16 over vbf+bq0
  u16* o1 = bq1;                  // after scores, aq is dead

  const dim3 blk(256);

  cvt_bf16_kernel<<<dim3((int)(SZ / 4 / 256)), blk, 0, stream>>>(x, xbf,
                                                                 (int)(SZ / 4));
  cvt_bf16_kernel<<<dim3(3 * 1024), blk, 0, stream>>>(Wqkv, wqkvb,
                                                      3 * 1024 * 1024 / 4);
  cvt_bf16_kernel<<<dim3(1024), blk, 0, stream>>>(Wout, woutb,
                                                  1024 * 1024 / 4);
  prep_G_bf16_kernel<<<dim3(4096), blk, 0, stream>>>(Gq_raw, gqb);
  prep_G_bf16_kernel<<<dim3(4096), blk, 0, stream>>>(Gk_raw, gkb);

  // qkv: 1536 blocks, supertile-swizzled
  qkv_mfma_kernel<<<dim3(1536), blk, 0, stream>>>(xbf, wqkvb, uq, uk, vbf);
  // vT (xbf dead now)
  transpose_bf16_kernel<<<dim3(16, 32, 4), blk, 0, stream>>>(vbf, vT);

  // fused LCA: both chains, one dispatch
  lca_fused_kernel<<<dim3(512), blk, 0, stream>>>(uq, uk, gqb, gkb, llq, llk,
                                                  bq1, bkf);

  scores_mfma_kernel<<<dim3(16, 16, 4), blk, 0, stream>>>(bq1, bkf, sc);
  softmax_attn_kernel<<<dim3(B_DIM * T_DIM), blk, 0, stream>>>(sc, attn);
  attnv_mfma_kernel<<<dim3(8, 16, 4), blk, 0, stream>>>(attn, vT, o1);
  out_mfma_kernel<<<dim3(8, 64), blk, 0, stream>>>(o1, woutb, out);
}